// Round 10
// baseline (136.183 us; speedup 1.0000x reference)
//
#include <hip/hip_runtime.h>

// TopicRouter: logits = h @ gate_w^T + gate_b ; top-2 ; softmax over top-2.
// Outputs flat in d_out (float32): [0, 2B)   = topk indices as floats
//                                  [2B, 4B)  = softmax weights
//
// R10 design — thread-per-token + global_load_lds DMA streaming:
//  * R9 (wave-per-token, wf in 96 VGPRs) = 104 us; structural ceiling: weight
//    cache pins VGPR>=130 (3-4 waves/SIMD) and every token pays a dependent
//    6-level DS shuffle chain. 60% above the ~65 us memory floor.
//  * Here: thread owns a token; 8 f32 accs in-register; ZERO cross-lane ops.
//    h transposed through LDS via global_load_lds (coalesced source, linear
//    dest). 512 blocks x 256 tokens = whole grid co-resident (2 blocks/CU).
//  * Chunks of 12 dims (12 KB/chunk), 3-deep buffer rotation, counted
//    s_waitcnt vmcnt(3) + raw s_barrier per chunk (never drain in-loop;
//    __syncthreads only in prologue). 12-float rows: granule quad =
//    (3t+g')&7, 3 coprime 8 -> 8-way bank spread (b128 floor).
//  * Weights in LDS (broadcast ds_reads), NOT global/scalar loads: any VMEM
//    op inside the loop would corrupt the vmcnt counting. bias loaded before
//    the prologue drain for the same reason.
//  * f32 + flag + separate f64 repair kernel (R9-proven): one top-2 rank
//    flip vs the f64 np ref fails the 0.14 idx threshold; f32 path error
//    ~1e-6 vs TAU=1e-4 ambiguity margin; ~1e-3 trigger rate.

#define B_TOKENS 131072
#define DM 768
#define NE 8
#define TAU 1e-4f
#define TPB 256
#define CH 12          // dims per chunk
#define NCH 64         // 768 / 12
#define HBUF 3072      // floats per chunk buffer (256 tokens * 12 dims)

typedef const __attribute__((address_space(1))) void* gbl_vp;
typedef __attribute__((address_space(3))) void* lds_vp;

__device__ __forceinline__ void dma16(const float* g, float* l) {
    __builtin_amdgcn_global_load_lds((gbl_vp)g, (lds_vp)l, 16, 0, 0);
}

__global__ __launch_bounds__(256) void router_main(
    const float* __restrict__ h,     // [B, 768]
    const float* __restrict__ gw,    // [8, 768]
    const float* __restrict__ gb,    // [8]
    float* __restrict__ out,         // [2B idx floats][2B weight floats]
    unsigned char* __restrict__ flags)
{
    __shared__ __align__(16) float w_lds[NE * DM];   // 24 KB
    __shared__ __align__(16) float h_lds[3 * HBUF];  // 36 KB

    const int tid  = threadIdx.x;
    const int lane = tid & 63;
    const int wv   = __builtin_amdgcn_readfirstlane(tid >> 6);
    const int tb   = blockIdx.x * TPB;

    // ---- per-lane DMA source addresses (slot sigma = wv*192 + i*64 + lane;
    //      slot holds h[tb + sigma/3][chunk*12 + (sigma%3)*4 ..+3]) ----
    const float* src[3];
#pragma unroll
    for (int i = 0; i < 3; ++i) {
        const int sigma = wv * 192 + i * 64 + lane;
        const int r = sigma / 3, g = sigma % 3;
        src[i] = h + (size_t)(tb + r) * DM + g * 4;
    }
    // wave-uniform LDS float offset for instr i (within a chunk buffer)
    const int dstoff0 = wv * 768;   // + i*256

    // ---- prologue: issue D0, D1; stage w; load bias; full drain ----
    dma16(src[0], &h_lds[0 * HBUF + dstoff0 + 0]);
    dma16(src[1], &h_lds[0 * HBUF + dstoff0 + 256]);
    dma16(src[2], &h_lds[0 * HBUF + dstoff0 + 512]);
#pragma unroll
    for (int i = 0; i < 3; ++i)
        dma16(src[i] + CH, &h_lds[1 * HBUF + dstoff0 + i * 256]);
#pragma unroll
    for (int i = 0; i < 3; ++i) src[i] += 2 * CH;   // next chunk to issue: 2

    // stage gate_w: 1536 float4, 6 per thread (coalesced)
#pragma unroll
    for (int s = 0; s < 6; ++s) {
        const float4 v = *reinterpret_cast<const float4*>(&gw[(tid + s * TPB) * 4]);
        *reinterpret_cast<float4*>(&w_lds[(tid + s * TPB) * 4]) = v;
    }
    float bias[NE];
#pragma unroll
    for (int e = 0; e < NE; ++e) bias[e] = gb[e];   // pre-drain: no VMEM later

    __syncthreads();   // full vmcnt/lgkm drain + barrier (once, prologue only)

    // ---- main loop: counted vmcnt, raw barrier, 3-buffer rotation ----
    float acc[NE] = {0, 0, 0, 0, 0, 0, 0, 0};

    for (int k = 0; k < NCH; ++k) {
        if (k == NCH - 1) {
            asm volatile("s_waitcnt vmcnt(0)" ::: "memory");
        } else {
            asm volatile("s_waitcnt vmcnt(3)" ::: "memory");
        }
        __builtin_amdgcn_s_barrier();
        __builtin_amdgcn_sched_barrier(0);

        if (k + 2 < NCH) {
            float* dst = &h_lds[((k + 2) % 3) * HBUF + dstoff0];
            dma16(src[0], dst);
            dma16(src[1], dst + 256);
            dma16(src[2], dst + 512);
#pragma unroll
            for (int i = 0; i < 3; ++i) src[i] += CH;
        }
        __builtin_amdgcn_sched_barrier(0);

        const float* row = &h_lds[(k % 3) * HBUF + tid * CH];
        const int wbase = k * CH;
#pragma unroll
        for (int g2 = 0; g2 < 3; ++g2) {
            const float4 hv = *reinterpret_cast<const float4*>(&row[g2 * 4]);
#pragma unroll
            for (int e = 0; e < NE; ++e) {
                const float4 wv4 = *reinterpret_cast<const float4*>(
                    &w_lds[e * DM + wbase + g2 * 4]);
                acc[e] = fmaf(hv.x, wv4.x, acc[e]);
                acc[e] = fmaf(hv.y, wv4.y, acc[e]);
                acc[e] = fmaf(hv.z, wv4.z, acc[e]);
                acc[e] = fmaf(hv.w, wv4.w, acc[e]);
            }
        }
    }

    // ---- epilogue: bias, top-3, flag, softmax, write ----
    float lg[NE];
#pragma unroll
    for (int e = 0; e < NE; ++e) lg[e] = acc[e] + bias[e];

    int i0 = 0; float v0 = lg[0];
#pragma unroll
    for (int e = 1; e < NE; ++e)
        if (lg[e] > v0) { v0 = lg[e]; i0 = e; }
    int i1 = -1; float v1 = -3.4e38f;
#pragma unroll
    for (int e = 0; e < NE; ++e)
        if (e != i0 && lg[e] > v1) { v1 = lg[e]; i1 = e; }
    float v2 = -3.4e38f;
#pragma unroll
    for (int e = 0; e < NE; ++e)
        if (e != i0 && e != i1 && lg[e] > v2) v2 = lg[e];

    const bool amb = (v0 - v1 < TAU) || (v1 - v2 < TAU);

    const float ex = expf(v1 - v0);        // <= 1
    const float w1 = ex / (1.0f + ex);
    const float w0 = 1.0f - w1;

    const size_t t = (size_t)(tb + tid);
    *reinterpret_cast<float2*>(&out[2 * t]) = make_float2((float)i0, (float)i1);
    *reinterpret_cast<float2*>(&out[2 * (size_t)B_TOKENS + 2 * t]) =
        make_float2(w0, w1);
    flags[t] = amb ? 1 : 0;                // always written -> deterministic
}

// One wave per 64 consecutive tokens; early-exit when no flags set. (R9-proven.)
__global__ __launch_bounds__(256) void router_repair(
    const float* __restrict__ h,
    const float* __restrict__ gw,
    const float* __restrict__ gb,
    float* __restrict__ out,
    const unsigned char* __restrict__ flags)
{
    const int lane = threadIdx.x & 63;
    const int w = (blockIdx.x * blockDim.x + threadIdx.x) >> 6;
    const int t0 = w * 64;
    if (t0 >= B_TOKENS) return;

    const unsigned char f = flags[t0 + lane];
    unsigned long long mask = __ballot(f != 0);
    if (mask == 0ull) return;

    float wf[NE][3][4];
#pragma unroll
    for (int e = 0; e < NE; ++e)
#pragma unroll
        for (int g = 0; g < 3; ++g) {
            const float4 vv = *reinterpret_cast<const float4*>(
                &gw[e * DM + g * 256 + lane * 4]);
            wf[e][g][0] = vv.x; wf[e][g][1] = vv.y;
            wf[e][g][2] = vv.z; wf[e][g][3] = vv.w;
        }
    double biasd[NE];
#pragma unroll
    for (int e = 0; e < NE; ++e) biasd[e] = (double)gb[e];

    const bool hi32 = (lane & 32) != 0;
    const bool hi16 = (lane & 16) != 0;
    const bool hi8  = (lane & 8)  != 0;

    while (mask) {
        const int p = __ffsll(mask) - 1;
        mask &= (mask - 1);
        const int t = t0 + p;

        const float* hr = h + (size_t)t * DM;
        float4 buf[3];
#pragma unroll
        for (int g = 0; g < 3; ++g)
            buf[g] = *reinterpret_cast<const float4*>(&hr[g * 256 + lane * 4]);

        double acc[NE] = {0, 0, 0, 0, 0, 0, 0, 0};
#pragma unroll
        for (int g = 0; g < 3; ++g) {
            const float* bp = reinterpret_cast<const float*>(&buf[g]);
#pragma unroll
            for (int j = 0; j < 4; ++j) {
                const double hd = (double)bp[j];
#pragma unroll
                for (int e = 0; e < NE; ++e)
                    acc[e] = fma(hd, (double)wf[e][g][j], acc[e]);
            }
        }
        double d4[4];
#pragma unroll
        for (int j = 0; j < 4; ++j) {
            const double give = hi32 ? acc[j] : acc[4 + j];
            const double keep = hi32 ? acc[4 + j] : acc[j];
            d4[j] = keep + __shfl_xor(give, 32);
        }
        double d2[2];
#pragma unroll
        for (int j = 0; j < 2; ++j) {
            const double give = hi16 ? d4[j] : d4[2 + j];
            const double keep = hi16 ? d4[2 + j] : d4[j];
            d2[j] = keep + __shfl_xor(give, 16);
        }
        const double give = hi8 ? d2[0] : d2[1];
        const double keep = hi8 ? d2[1] : d2[0];
        double dv = keep + __shfl_xor(give, 8);
        dv += __shfl_xor(dv, 4);
        dv += __shfl_xor(dv, 2);
        dv += __shfl_xor(dv, 1);

        double dlg[NE];
#pragma unroll
        for (int e = 0; e < NE; ++e)
            dlg[e] = __shfl(dv, (e << 3) | (lane & 7)) + biasd[e];

        int i0 = 0; double dv0 = dlg[0];
#pragma unroll
        for (int e = 1; e < NE; ++e)
            if (dlg[e] > dv0) { dv0 = dlg[e]; i0 = e; }
        int i1 = (i0 == 0) ? 1 : 0; double dv1 = dlg[i1];
#pragma unroll
        for (int e = 0; e < NE; ++e)
            if (e != i0 && dlg[e] > dv1) { dv1 = dlg[e]; i1 = e; }

        const float ex = expf((float)(dv1 - dv0));
        const float w1 = ex / (1.0f + ex);
        const float w0 = 1.0f - w1;

        if (lane == 0) {
            *reinterpret_cast<float2*>(&out[2 * (size_t)t]) =
                make_float2((float)i0, (float)i1);
            *reinterpret_cast<float2*>(
                &out[2 * (size_t)B_TOKENS + 2 * (size_t)t]) =
                make_float2(w0, w1);
        }
    }
}

extern "C" void kernel_launch(void* const* d_in, const int* in_sizes, int n_in,
                              void* d_out, int out_size, void* d_ws, size_t ws_size,
                              hipStream_t stream) {
    const float* h  = (const float*)d_in[0];
    const float* gw = (const float*)d_in[1];
    const float* gb = (const float*)d_in[2];
    float* out = (float*)d_out;
    unsigned char* flags = (unsigned char*)d_ws;   // B_TOKENS bytes

    router_main<<<dim3(B_TOKENS / TPB), dim3(TPB), 0, stream>>>(h, gw, gb, out, flags);
    router_repair<<<dim3(512), dim3(256), 0, stream>>>(h, gw, gb, out, flags);
}

// Round 11
// 118.311 us; speedup vs baseline: 1.1511x; 1.1511x over previous
//
#include <hip/hip_runtime.h>

// TopicRouter: logits = h @ gate_w^T + gate_b ; top-2 ; softmax over top-2.
// Outputs flat in d_out (float32): [0, 2B)   = topk idx as floats
//                                  [2B, 4B)  = softmax weights
//
// R11 = R9 (wave-per-token, wf in 96 VGPRs, split-butterfly, 2-kernel f64
// repair; 104 us) + LDS-RESIDENT PREFETCH:
//  * R8 showed register prefetch/ILP crosses the 128-VGPR cliff (ILP vs TLP
//    trade on one RF). R10 showed thread-per-token forces per-thread LDS
//    weight re-reads (~3 GB DS traffic) -> dead end.
//  * Here: token rows prefetched depth-2 into per-wave PRIVATE LDS slots via
//    global_load_lds (3 slots x 3 KB/wave = 36 KB/block). In-flight storage
//    moves VGPR->LDS: kernel drops to ~120 VGPR -> 4 waves/SIMD, AND every
//    wave keeps 6-9 DMAs in flight (counted vmcnt(6), never drained mid-loop).
//    NO barriers in the loop (slots are wave-private).
//  * Compute per token: 3 conflict-free ds_read_b128 (lane*16B pattern),
//    96 f32 FMA vs the VGPR weight cache, 26-op butterfly+gather, top-3.
//  * f32 + flag + separate f64 repair kernel (R9-proven): one top-2 rank
//    flip vs the f64 np ref fails the 0.14 idx threshold; f32 path error
//    ~1e-6 vs TAU=1e-4 ambiguity margin; ~1e-3 trigger rate.

#define B_TOKENS 131072
#define DM 768
#define NE 8
#define TAU 1e-4f
#define NWAVES 4096         // 1024 blocks x 4 waves
#define NT 32               // tokens per wave = 131072 / 4096 (exact)

typedef const __attribute__((address_space(1))) void* gbl_vp;
typedef __attribute__((address_space(3))) void* lds_vp;

__device__ __forceinline__ void dma16(const float* g, float* l) {
    __builtin_amdgcn_global_load_lds((gbl_vp)g, (lds_vp)l, 16, 0, 0);
}

__global__ __launch_bounds__(256) void router_main(
    const float* __restrict__ h,     // [B, 768]
    const float* __restrict__ gw,    // [8, 768]
    const float* __restrict__ gb,    // [8]
    float* __restrict__ out,         // [2B idx floats][2B weight floats]
    unsigned char* __restrict__ flags)
{
    __shared__ __align__(16) float hslots[4][3][DM];   // 36 KB, wave-private slots

    const int tid  = threadIdx.x;
    const int lane = tid & 63;
    const int wv   = __builtin_amdgcn_readfirstlane(tid >> 6);
    const int wid  = blockIdx.x * 4 + (tid >> 6);      // global wave id, [0,4096)

    // ---- weight cache in VGPRs: wf[e][g] = gw[e][g*256 + lane*4 .. +3] ----
    float4 wf[NE][3];
#pragma unroll
    for (int e = 0; e < NE; ++e)
#pragma unroll
        for (int g = 0; g < 3; ++g)
            wf[e][g] = *reinterpret_cast<const float4*>(
                &gw[e * DM + g * 256 + lane * 4]);

    float biasf[NE];   // uniform -> SGPRs
#pragma unroll
    for (int e = 0; e < NE; ++e) biasf[e] = gb[e];

    // ---- DMA prologue: tokens k=0,1,2 into slots 0,1,2 (9 in flight) ----
#pragma unroll
    for (int kk = 0; kk < 3; ++kk) {
        const float* row = h + (size_t)(wid + kk * NWAVES) * DM;
#pragma unroll
        for (int i = 0; i < 3; ++i)
            dma16(row + i * 256 + lane * 4, &hslots[wv][kk][i * 256]);
    }

    const bool hi32 = (lane & 32) != 0;
    const bool hi16 = (lane & 16) != 0;
    const bool hi8  = (lane & 8)  != 0;

    for (int k = 0; k < NT; ++k) {
        const int t = wid + k * NWAVES;

        // counted wait: keep the 2 newer tokens' DMAs (6) in flight
        if (k <= NT - 3)      asm volatile("s_waitcnt vmcnt(6)" ::: "memory");
        else if (k == NT - 2) asm volatile("s_waitcnt vmcnt(3)" ::: "memory");
        else                  asm volatile("s_waitcnt vmcnt(0)" ::: "memory");

        // ---- read this token's 12 dims from the slot (3x ds_read_b128) ----
        const float* slot = &hslots[wv][k % 3][0];
        const float4 h0 = *reinterpret_cast<const float4*>(&slot[0 + lane * 4]);
        const float4 h1 = *reinterpret_cast<const float4*>(&slot[256 + lane * 4]);
        const float4 h2 = *reinterpret_cast<const float4*>(&slot[512 + lane * 4]);

        // data must be in regs before we re-DMA into this slot
        asm volatile("s_waitcnt lgkmcnt(0)" ::: "memory");
        __builtin_amdgcn_sched_barrier(0);

        // ---- reissue: token k+3 into the slot just freed ----
        if (k + 3 < NT) {
            const float* row = h + (size_t)(t + 3 * NWAVES) * DM;
            float* dst = &hslots[wv][k % 3][0];
#pragma unroll
            for (int i = 0; i < 3; ++i)
                dma16(row + i * 256 + lane * 4, dst + i * 256);
        }
        __builtin_amdgcn_sched_barrier(0);

        // ---- f32 partial dot: 96 FMAs/lane ----
        float accf[NE] = {0, 0, 0, 0, 0, 0, 0, 0};
#pragma unroll
        for (int e = 0; e < NE; ++e) {
            accf[e] = fmaf(h0.x, wf[e][0].x, accf[e]);
            accf[e] = fmaf(h0.y, wf[e][0].y, accf[e]);
            accf[e] = fmaf(h0.z, wf[e][0].z, accf[e]);
            accf[e] = fmaf(h0.w, wf[e][0].w, accf[e]);
            accf[e] = fmaf(h1.x, wf[e][1].x, accf[e]);
            accf[e] = fmaf(h1.y, wf[e][1].y, accf[e]);
            accf[e] = fmaf(h1.z, wf[e][1].z, accf[e]);
            accf[e] = fmaf(h1.w, wf[e][1].w, accf[e]);
            accf[e] = fmaf(h2.x, wf[e][2].x, accf[e]);
            accf[e] = fmaf(h2.y, wf[e][2].y, accf[e]);
            accf[e] = fmaf(h2.z, wf[e][2].z, accf[e]);
            accf[e] = fmaf(h2.w, wf[e][2].w, accf[e]);
        }

        // ---- f32 split-butterfly reduce (18 b32 DS ops) ----
        float r4[4];
#pragma unroll
        for (int j = 0; j < 4; ++j) {
            const float give = hi32 ? accf[j] : accf[4 + j];
            const float keep = hi32 ? accf[4 + j] : accf[j];
            r4[j] = keep + __shfl_xor(give, 32);
        }
        float r2[2];
#pragma unroll
        for (int j = 0; j < 2; ++j) {
            const float give = hi16 ? r4[j] : r4[2 + j];
            const float keep = hi16 ? r4[2 + j] : r4[j];
            r2[j] = keep + __shfl_xor(give, 16);
        }
        const float give = hi8 ? r2[0] : r2[1];
        const float keep = hi8 ? r2[1] : r2[0];
        float v = keep + __shfl_xor(give, 8);
        v += __shfl_xor(v, 4);
        v += __shfl_xor(v, 2);
        v += __shfl_xor(v, 1);

        // gather all 8 logits into every lane (identical across lanes)
        float lg[NE];
#pragma unroll
        for (int e = 0; e < NE; ++e)
            lg[e] = __shfl(v, (e << 3) | (lane & 7)) + biasf[e];

        // ---- f32 top-3 (lax.top_k tie-break: lower index wins) ----
        int i0 = 0; float v0 = lg[0];
#pragma unroll
        for (int e = 1; e < NE; ++e)
            if (lg[e] > v0) { v0 = lg[e]; i0 = e; }
        int i1 = -1; float v1 = -3.4e38f;
#pragma unroll
        for (int e = 0; e < NE; ++e)
            if (e != i0 && lg[e] > v1) { v1 = lg[e]; i1 = e; }
        float v2 = -3.4e38f;
#pragma unroll
        for (int e = 0; e < NE; ++e)
            if (e != i0 && e != i1 && lg[e] > v2) v2 = lg[e];

        const bool amb = (v0 - v1 < TAU) || (v1 - v2 < TAU);

        const float ex = expf(v1 - v0);    // <= 1
        const float w1 = ex / (1.0f + ex);
        const float w0 = 1.0f - w1;

        if (lane == 0) {
            *reinterpret_cast<float2*>(&out[2 * (size_t)t]) =
                make_float2((float)i0, (float)i1);
            *reinterpret_cast<float2*>(
                &out[2 * (size_t)B_TOKENS + 2 * (size_t)t]) =
                make_float2(w0, w1);
            flags[t] = amb ? 1 : 0;        // always written -> deterministic
        }
    }
}

// One wave per 64 consecutive tokens; early-exit when no flags set. (R9-proven.)
__global__ __launch_bounds__(256) void router_repair(
    const float* __restrict__ h,
    const float* __restrict__ gw,
    const float* __restrict__ gb,
    float* __restrict__ out,
    const unsigned char* __restrict__ flags)
{
    const int lane = threadIdx.x & 63;
    const int w = (blockIdx.x * blockDim.x + threadIdx.x) >> 6;
    const int t0 = w * 64;
    if (t0 >= B_TOKENS) return;

    const unsigned char f = flags[t0 + lane];
    unsigned long long mask = __ballot(f != 0);
    if (mask == 0ull) return;

    float wf[NE][3][4];
#pragma unroll
    for (int e = 0; e < NE; ++e)
#pragma unroll
        for (int g = 0; g < 3; ++g) {
            const float4 vv = *reinterpret_cast<const float4*>(
                &gw[e * DM + g * 256 + lane * 4]);
            wf[e][g][0] = vv.x; wf[e][g][1] = vv.y;
            wf[e][g][2] = vv.z; wf[e][g][3] = vv.w;
        }
    double biasd[NE];
#pragma unroll
    for (int e = 0; e < NE; ++e) biasd[e] = (double)gb[e];

    const bool hi32 = (lane & 32) != 0;
    const bool hi16 = (lane & 16) != 0;
    const bool hi8  = (lane & 8)  != 0;

    while (mask) {
        const int p = __ffsll(mask) - 1;
        mask &= (mask - 1);
        const int t = t0 + p;

        const float* hr = h + (size_t)t * DM;
        float4 buf[3];
#pragma unroll
        for (int g = 0; g < 3; ++g)
            buf[g] = *reinterpret_cast<const float4*>(&hr[g * 256 + lane * 4]);

        double acc[NE] = {0, 0, 0, 0, 0, 0, 0, 0};
#pragma unroll
        for (int g = 0; g < 3; ++g) {
            const float* bp = reinterpret_cast<const float*>(&buf[g]);
#pragma unroll
            for (int j = 0; j < 4; ++j) {
                const double hd = (double)bp[j];
#pragma unroll
                for (int e = 0; e < NE; ++e)
                    acc[e] = fma(hd, (double)wf[e][g][j], acc[e]);
            }
        }
        double d4[4];
#pragma unroll
        for (int j = 0; j < 4; ++j) {
            const double give = hi32 ? acc[j] : acc[4 + j];
            const double keep = hi32 ? acc[4 + j] : acc[j];
            d4[j] = keep + __shfl_xor(give, 32);
        }
        double d2[2];
#pragma unroll
        for (int j = 0; j < 2; ++j) {
            const double give = hi16 ? d4[j] : d4[2 + j];
            const double keep = hi16 ? d4[2 + j] : d4[j];
            d2[j] = keep + __shfl_xor(give, 16);
        }
        const double give = hi8 ? d2[0] : d2[1];
        const double keep = hi8 ? d2[1] : d2[0];
        double dv = keep + __shfl_xor(give, 8);
        dv += __shfl_xor(dv, 4);
        dv += __shfl_xor(dv, 2);
        dv += __shfl_xor(dv, 1);

        double dlg[NE];
#pragma unroll
        for (int e = 0; e < NE; ++e)
            dlg[e] = __shfl(dv, (e << 3) | (lane & 7)) + biasd[e];

        int i0 = 0; double dv0 = dlg[0];
#pragma unroll
        for (int e = 1; e < NE; ++e)
            if (dlg[e] > dv0) { dv0 = dlg[e]; i0 = e; }
        int i1 = (i0 == 0) ? 1 : 0; double dv1 = dlg[i1];
#pragma unroll
        for (int e = 0; e < NE; ++e)
            if (e != i0 && dlg[e] > dv1) { dv1 = dlg[e]; i1 = e; }

        const float ex = expf((float)(dv1 - dv0));
        const float w1 = ex / (1.0f + ex);
        const float w0 = 1.0f - w1;

        if (lane == 0) {
            *reinterpret_cast<float2*>(&out[2 * (size_t)t]) =
                make_float2((float)i0, (float)i1);
            *reinterpret_cast<float2*>(
                &out[2 * (size_t)B_TOKENS + 2 * (size_t)t]) =
                make_float2(w0, w1);
        }
    }
}

extern "C" void kernel_launch(void* const* d_in, const int* in_sizes, int n_in,
                              void* d_out, int out_size, void* d_ws, size_t ws_size,
                              hipStream_t stream) {
    const float* h  = (const float*)d_in[0];
    const float* gw = (const float*)d_in[1];
    const float* gb = (const float*)d_in[2];
    float* out = (float*)d_out;
    unsigned char* flags = (unsigned char*)d_ws;   // B_TOKENS bytes

    router_main<<<dim3(1024), dim3(256), 0, stream>>>(h, gw, gb, out, flags);
    router_repair<<<dim3(512), dim3(256), 0, stream>>>(h, gw, gb, out, flags);
}